// Round 6
// baseline (196.785 us; speedup 1.0000x reference)
//
#include <hip/hip_runtime.h>

// MSDeformAttn: B=4, Lq=Lv=5440 (M=21760), C=256, heads=8, levels=4, points=4, hd=32
// Level shapes: (64,64),(32,32),(16,16),(8,8) -> starts 0,4096,5120,5376
//
// R15: one-shot K=256 gemm12 + frag-major f16 weights (prep_w).
//  - R9/R11/R13 all pin gemm12 at ~43+-2us across occ 13/20/29% -> occupancy-
//    independent wall = transaction density + per-kt vmcnt(0) barrier drain.
//    (A loads: 64 lines/instr at 16B used; B: 16 strided dwords/thread;
//    __syncthreads drains the "prefetch" every kt.)
//  - R15: prep_w converts W_val/W_off/W_attn to f16 frag-major 64-col tiles
//    (320KB). gemm12: 64x64 tile, WHOLE K staged once: A 4 lanes/row (64
//    contiguous f32/lane = dense lines), cvt, frag-major LDS; B = linear
//    32KB global_load_lds copy. ONE barrier, then 32 MFMA/wave. Grid 3400,
//    nt-fastest for A-panel L2 reuse. LDS 64KB (2 blocks/CU, sync~0).
//  - Predict: gemm12 44 -> 15-22us, MfmaUtil ~15%, FETCH/WRITE ~flat.
//  - sample_f16 / gemm_single byte-identical to R14.

typedef __attribute__((ext_vector_type(8))) _Float16 half8;
typedef __attribute__((ext_vector_type(4))) _Float16 half4;
typedef __attribute__((ext_vector_type(4))) float f32x4;

typedef __attribute__((address_space(3))) unsigned int lds_uint;
typedef const __attribute__((address_space(1))) unsigned int g_uint;

__device__ __forceinline__ void load_lds16(const _Float16* g, _Float16* l) {
    __builtin_amdgcn_global_load_lds((g_uint*)g, (lds_uint*)l, 16, 0, 0);
}

__device__ __forceinline__ half8 splat8(_Float16 v) {
    half8 r = {v, v, v, v, v, v, v, v};
    return r;
}

#define M_TOTAL 21760

// -------- prep_w: weights -> f16, fragment-major per 64-col tile --------------
// wtf layout: tile T (0..3: W_val cols T*64..; 4..9: [W_off|W_attn] cols
// (T-4)*64..), slot = (T*32 + g)*64 + nl, 8 f16 per slot (k = g*8+e).
__global__ __launch_bounds__(256) void prep_w(
    const float* __restrict__ W_val, const float* __restrict__ W_off,
    const float* __restrict__ W_attn, _Float16* __restrict__ wtf)
{
    const int slot = blockIdx.x * 256 + threadIdx.x;   // 0..20479
    const int T = slot >> 11;
    const int rem = slot & 2047;
    const int g = rem >> 6, nl = rem & 63;
    half8 h;
#pragma unroll
    for (int e = 0; e < 8; ++e) {
        const int k = g * 8 + e;
        float v;
        if (T < 4) {
            v = W_val[k * 256 + T * 64 + nl];
        } else {
            const int n2 = (T - 4) * 64 + nl;
            v = (n2 < 256) ? W_off[k * 256 + n2] : W_attn[k * 128 + (n2 - 256)];
        }
        h[e] = (_Float16)v;
    }
    *(half8*)(wtf + ((size_t)slot << 3)) = h;
}

// -------- fused GEMM1+GEMM2, 64x64 tiles, one-shot K=256 ----------------------
__global__ __launch_bounds__(256) void gemm12_cvt(
    const float* __restrict__ value, const float* __restrict__ query,
    const _Float16* __restrict__ wtf,
    const float* __restrict__ b_val, const float* __restrict__ b_off,
    const float* __restrict__ b_attn,
    _Float16* __restrict__ valh, _Float16* __restrict__ offh)
{
    __shared__ _Float16 Afs[32 * 64 * 8];   // 32KB: [g 0..31][row 0..63][8]
    __shared__ _Float16 Bfs[32 * 64 * 8];   // 32KB: [g 0..31][col 0..63][8]

    const bool g1 = blockIdx.x < 1360;
    const int id = g1 ? blockIdx.x : blockIdx.x - 1360;
    const int mt = g1 ? (id >> 2) : (id / 6);
    const int nt = g1 ? (id & 3) : (id % 6);
    const int NN = g1 ? 256 : 384;
    const float* A = g1 ? value : query;
    _Float16* C = g1 ? valh : offh;
    const int bm = mt * 64;
    const int bn = nt * 64;
    const int T  = g1 ? nt : 4 + nt;

    const int tid = threadIdx.x;
    const int wave = tid >> 6, lane = tid & 63;
    const int ml = lane & 15, q = lane >> 4;

    // ---- B: linear 32KB copy (dense lines) via global_load_lds -----------
    const _Float16* wsrc = wtf + ((size_t)T << 14);    // T * 2048 slots * 8
#pragma unroll
    for (int i = 0; i < 8; ++i)
        load_lds16(wsrc + (((size_t)i * 256 + tid) << 3),
                   Bfs + (((size_t)i * 256 + wave * 64) << 3));

    // ---- A: dense row-chunk loads (4 lanes/row) + cvt + frag-major write --
    {
        const int r = tid >> 2, c4 = tid & 3;
        const float* ap = A + (size_t)(bm + r) * 256 + c4 * 64;
        float4 pa[16];
#pragma unroll
        for (int j = 0; j < 16; ++j) pa[j] = *(const float4*)(ap + j * 4);
#pragma unroll
        for (int u = 0; u < 8; ++u) {
            const float4 a0 = pa[2 * u], a1 = pa[2 * u + 1];
            const half8 h = {(_Float16)a0.x, (_Float16)a0.y, (_Float16)a0.z, (_Float16)a0.w,
                             (_Float16)a1.x, (_Float16)a1.y, (_Float16)a1.z, (_Float16)a1.w};
            *(half8*)(Afs + (((c4 * 8 + u) * 64 + r) << 3)) = h;
        }
    }
    __syncthreads();   // the ONLY barrier (drains DMA + ds_writes)

    const f32x4 zero4 = {0.f, 0.f, 0.f, 0.f};
    f32x4 acc[4] = {zero4, zero4, zero4, zero4};

#pragma unroll
    for (int kt = 0; kt < 8; ++kt) {
        const int g = kt * 4 + q;
        const half8 af = *(const half8*)(Afs + (((size_t)g * 64 + wave * 16 + ml) << 3));
#pragma unroll
        for (int j = 0; j < 4; ++j) {
            const half8 bf = *(const half8*)(Bfs + (((size_t)g * 64 + j * 16 + ml) << 3));
            acc[j] = __builtin_amdgcn_mfma_f32_16x16x32_f16(af, bf, acc[j], 0, 0, 0);
        }
    }

    const int r0 = q * 4;
#pragma unroll
    for (int j = 0; j < 4; ++j) {
        const int col = bn + j * 16 + ml;
        const float bj = g1 ? b_val[col] : (col < 256 ? b_off[col] : b_attn[col - 256]);
        const size_t rbase = (size_t)(bm + wave * 16 + r0) * NN + col;
#pragma unroll
        for (int r = 0; r < 4; ++r)
            C[rbase + (size_t)r * NN] = (_Float16)(acc[j][r] + bj);
    }
}

// -------- R4 GEMM core (DMA staging, pitch 32) for the final GEMM -------------
__device__ __forceinline__ void gemm_core(
    const _Float16* __restrict__ A, const _Float16* __restrict__ Bt,
    const float* __restrict__ bias, float* __restrict__ Cv,
    int NN, int mt, int nt)
{
    __shared__ _Float16 Ah[128 * 32];
    __shared__ _Float16 Bh[64 * 32];

    const int tid = threadIdx.x;
    const int bm = mt * 128;
    const int bn = nt * 64;
    const int wave = tid >> 6, lane = tid & 63;
    const int wm = (wave & 1) * 64, wn = (wave >> 1) * 32;
    const int ml = lane & 15, kq = (lane >> 4) * 8;
    const int lr = lane >> 2;
    const int lk = (lane & 3) * 8;

    const f32x4 zero4 = {0.f, 0.f, 0.f, 0.f};
    f32x4 acc[4][2];
#pragma unroll
    for (int i = 0; i < 4; ++i)
#pragma unroll
        for (int j = 0; j < 2; ++j) acc[i][j] = zero4;

    for (int kt = 0; kt < 8; ++kt) {
        const int k0 = kt * 32;
        __syncthreads();
#pragma unroll
        for (int t = 0; t < 2; ++t) {
            const int row = wave * 32 + t * 16;
            load_lds16(A + (size_t)(bm + row + lr) * 256 + k0 + lk,
                       Ah + (size_t)row * 32);
        }
        {
            const int row = wave * 16;
            load_lds16(Bt + (size_t)(bn + row + lr) * 256 + k0 + lk,
                       Bh + (size_t)row * 32);
        }
        __syncthreads();

        half8 af[4], bf[2];
#pragma unroll
        for (int i = 0; i < 4; ++i)
            af[i] = *(const half8*)(Ah + (wm + i * 16 + ml) * 32 + kq);
#pragma unroll
        for (int j = 0; j < 2; ++j)
            bf[j] = *(const half8*)(Bh + (wn + j * 16 + ml) * 32 + kq);
#pragma unroll
        for (int i = 0; i < 4; ++i)
#pragma unroll
            for (int j = 0; j < 2; ++j)
                acc[i][j] = __builtin_amdgcn_mfma_f32_16x16x32_f16(af[i], bf[j], acc[i][j], 0, 0, 0);
    }

    const int r0 = (lane >> 4) * 4;
#pragma unroll
    for (int j = 0; j < 2; ++j) {
        const int col = bn + wn + j * 16 + ml;
        const float bj = bias[col];
#pragma unroll
        for (int i = 0; i < 4; ++i) {
            const size_t rbase = (size_t)(bm + wm + i * 16 + r0) * NN + col;
#pragma unroll
            for (int r = 0; r < 4; ++r)
                Cv[rbase + (size_t)r * NN] = acc[i][j][r] + bj;
        }
    }
}

__global__ __launch_bounds__(256) void gemm_single(
    const _Float16* __restrict__ A, const _Float16* __restrict__ Bt,
    const float* __restrict__ bias, float* __restrict__ Cv)
{
    const int id = blockIdx.x;
    gemm_core(A, Bt, bias, Cv, 256, id >> 2, id & 3);
}

// ---------------- sampler: group-dedup'd scalar phase + batched gathers -------
__global__ __launch_bounds__(256, 4) void sample_f16(
    const _Float16* __restrict__ valh,   // [M,256] f16
    const float* __restrict__ refp,      // [B,Lq,4,2]
    const _Float16* __restrict__ offh,   // [M,384] f16: 0-255 offsets, 256-383 logits
    const float* __restrict__ W_out,     // [256,256] f32 (k-major)
    _Float16* __restrict__ wto,          // [256,256] f16 (n-major, k-contig)
    _Float16* __restrict__ acc_out)      // [M,256] f16
{
    // fold W_out transpose into the first 256 blocks (consumed next dispatch)
    if (blockIdx.x < 256)
        wto[blockIdx.x * 256 + threadIdx.x] =
            (_Float16)W_out[threadIdx.x * 256 + blockIdx.x];

    const int wave = threadIdx.x >> 6, lane = threadIdx.x & 63;
    const int q2 = lane >> 5, sl = lane & 31;
    const int bq = blockIdx.x * 8 + wave * 2 + q2;    // 0..21759
    const int b = bq / 5440;
    const int h = sl >> 2;          // head
    const int t = sl & 3;           // dual role: my LEVEL (scalar phase) and d8 octet (gather)
    const int d8 = t * 8;

    // ---------- scalar phase: lane t computes level t's 4 points ----------
    const int Wt = 64 >> t;                       // {64,32,16,8}
    const float fW = (float)Wt;

    const half8 ofr = *(const half8*)(offh + (size_t)bq * 384 + h * 32 + t * 8);
    const half4 lgt = *(const half4*)(offh + (size_t)bq * 384 + 256 + h * 16 + t * 4);
    const float2 rxy = *(const float2*)(refp + (size_t)bq * 8 + t * 2);

    float lg[4];
#pragma unroll
    for (int p = 0; p < 4; ++p) lg[p] = (float)lgt[p];

    // group softmax: 4-lane butterfly (lanes t=0..3 share (bq,h))
    float mx = fmaxf(fmaxf(lg[0], lg[1]), fmaxf(lg[2], lg[3]));
    mx = fmaxf(mx, __shfl_xor(mx, 1));
    mx = fmaxf(mx, __shfl_xor(mx, 2));
    float s = 0.f;
#pragma unroll
    for (int p = 0; p < 4; ++p) { lg[p] = __expf(lg[p] - mx); s += lg[p]; }
    s += __shfl_xor(s, 1);
    s += __shfl_xor(s, 2);
    const float inv = 1.f / s;

    // per-corner pack: row(<=4095) << 16 | f16(weight)
    unsigned pk[16];
#pragma unroll
    for (int p = 0; p < 4; ++p) {
        const float aw = lg[p] * inv;
        const float ox = (float)ofr[p * 2];
        const float oy = (float)ofr[p * 2 + 1];
        const float x = fmaf(rxy.x, fW, ox) - 0.5f;
        const float y = fmaf(rxy.y, fW, oy) - 0.5f;
        const float x0f = floorf(x), y0f = floorf(y);
        const int x0 = (int)x0f, y0 = (int)y0f;
        const float wx = x - x0f, wy = y - y0f;
        const bool okx0 = ((unsigned)x0 < (unsigned)Wt);
        const bool okx1 = ((unsigned)(x0 + 1) < (unsigned)Wt);
        const bool oky0 = ((unsigned)y0 < (unsigned)Wt);
        const bool oky1 = ((unsigned)(y0 + 1) < (unsigned)Wt);
        const int xc0 = min(max(x0, 0), Wt - 1);
        const int xc1 = min(max(x0 + 1, 0), Wt - 1);
        const int yc0 = min(max(y0, 0), Wt - 1);
        const int yc1 = min(max(y0 + 1, 0), Wt - 1);
        const _Float16 w0 = (_Float16)((okx0 & oky0) ? (1.f - wx) * (1.f - wy) * aw : 0.f);
        const _Float16 w1 = (_Float16)((okx1 & oky0) ? wx * (1.f - wy) * aw : 0.f);
        const _Float16 w2 = (_Float16)((okx0 & oky1) ? (1.f - wx) * wy * aw : 0.f);
        const _Float16 w3 = (_Float16)((okx1 & oky1) ? wx * wy * aw : 0.f);
        pk[p * 4 + 0] = ((unsigned)(yc0 * Wt + xc0) << 16) |
                        (unsigned)__builtin_bit_cast(unsigned short, w0);
        pk[p * 4 + 1] = ((unsigned)(yc0 * Wt + xc1) << 16) |
                        (unsigned)__builtin_bit_cast(unsigned short, w1);
        pk[p * 4 + 2] = ((unsigned)(yc1 * Wt + xc0) << 16) |
                        (unsigned)__builtin_bit_cast(unsigned short, w2);
        pk[p * 4 + 3] = ((unsigned)(yc1 * Wt + xc1) << 16) |
                        (unsigned)__builtin_bit_cast(unsigned short, w3);
    }

    // ---------- gather phase: all lanes, per level, via group exchange ----
    const int starts_[4] = {0, 4096, 5120, 5376};
    const int gbase = lane & ~3;                  // group leader lane

    half8 acc = splat8((_Float16)0.f);
#pragma unroll
    for (int l = 0; l < 4; ++l) {
        const _Float16* vbase = valh + ((size_t)(b * 5440 + starts_[l])) * 256 + h * 32 + d8;
        const int src = gbase + l;

        unsigned q_[16];
#pragma unroll
        for (int c = 0; c < 16; ++c)
            q_[c] = (unsigned)__shfl((int)pk[c], src);

        // pin: all 16 loads issue before any consumer (progressive vmcnt drain)
        __builtin_amdgcn_sched_barrier(0);
        half8 c_[16];
#pragma unroll
        for (int c = 0; c < 16; ++c)
            c_[c] = *(const half8*)(vbase + ((size_t)(q_[c] >> 16) << 8));
        __builtin_amdgcn_sched_barrier(0);
#pragma unroll
        for (int c = 0; c < 16; ++c)
            acc += c_[c] * splat8(__builtin_bit_cast(_Float16, (unsigned short)(q_[c] & 0xffffu)));
    }

    *(half8*)(acc_out + (size_t)bq * 256 + h * 32 + d8) = acc;
}

extern "C" void kernel_launch(void* const* d_in, const int* in_sizes, int n_in,
                              void* d_out, int out_size, void* d_ws, size_t ws_size,
                              hipStream_t stream) {
    const float* query  = (const float*)d_in[0];
    const float* refp   = (const float*)d_in[1];
    const float* value  = (const float*)d_in[2];
    const float* W_off  = (const float*)d_in[3];
    const float* b_off  = (const float*)d_in[4];
    const float* W_attn = (const float*)d_in[5];
    const float* b_attn = (const float*)d_in[6];
    const float* W_val  = (const float*)d_in[7];
    const float* b_val  = (const float*)d_in[8];
    const float* W_out  = (const float*)d_in[9];
    const float* b_out  = (const float*)d_in[10];
    float* out = (float*)d_out;

    const size_t M = M_TOTAL;

    _Float16* valh  = (_Float16*)d_ws;                // M*256
    _Float16* offh  = valh + M * 256;                 // M*384
    _Float16* acc16 = offh + M * 384;                 // M*256
    _Float16* wto   = acc16 + M * 256;                // 256*256
    _Float16* wtf   = wto + 256 * 256;                // 10*32*64*8 = 163840

    dim3 blk(256);
    prep_w<<<dim3(80), blk, 0, stream>>>(W_val, W_off, W_attn, wtf);
    gemm12_cvt<<<dim3(3400), blk, 0, stream>>>(
        value, query, wtf, b_val, b_off, b_attn, valh, offh);
    sample_f16<<<dim3(M / 8), blk, 0, stream>>>(valh, refp, offh, W_out, wto, acc16);
    gemm_single<<<dim3(680), blk, 0, stream>>>(acc16, wto, b_out, out);
}

// Round 7
// 178.596 us; speedup vs baseline: 1.1018x; 1.1018x over previous
//
#include <hip/hip_runtime.h>

// MSDeformAttn: B=4, Lq=Lv=5440 (M=21760), C=256, heads=8, levels=4, points=4, hd=32
// Level shapes: (64,64),(32,32),(16,16),(8,8) -> starts 0,4096,5120,5376
//
// R16: gemm12 rebuilt around per-INSTRUCTION dense loads + zero barriers.
//  - R15 post-mortem: (a) A loads still 64 lines/instr (coalescing is
//    across lanes, not per-lane); (b) frag-major LDS reads 4-way bank
//    conflict (2.6M); (c) nt-fastest w/o XCD swizzle doubled FETCH (109MB);
//    (d) 64KB LDS -> 2 blocks/CU.
//  - R16 gemm12: one wave-instr = one full A row (lane i: float4 @ row*256
//    + i*4 -> 1KB contiguous, 16 dense lines, 16-deep MLP). A in row-major
//    LDS with G4 XOR swizzle (byte ^= (row&7)<<4) -> ds ops 2-way (free).
//    Wave-private rows -> ZERO barriers. B fragments direct from global
//    (frag-major wtf, L2-resident, 16 dense lines/instr), 2-deep prefetch.
//    XCD chunk swizzle (bid%8)*425+bid/8 -> A-panel reuse within one XCD.
//  - Predict: gemm12 62 -> 16-24us, FETCH ~50MB, conflicts ~0, total ~150.
//  - prep_w / sample_f16 / gemm_single byte-identical to R15.

typedef __attribute__((ext_vector_type(8))) _Float16 half8;
typedef __attribute__((ext_vector_type(4))) _Float16 half4;
typedef __attribute__((ext_vector_type(4))) float f32x4;

typedef __attribute__((address_space(3))) unsigned int lds_uint;
typedef const __attribute__((address_space(1))) unsigned int g_uint;

__device__ __forceinline__ void load_lds16(const _Float16* g, _Float16* l) {
    __builtin_amdgcn_global_load_lds((g_uint*)g, (lds_uint*)l, 16, 0, 0);
}

__device__ __forceinline__ half8 splat8(_Float16 v) {
    half8 r = {v, v, v, v, v, v, v, v};
    return r;
}

#define M_TOTAL 21760

// -------- prep_w: weights -> f16, fragment-major per 64-col tile --------------
// wtf layout: tile T (0..3: W_val cols T*64..; 4..9: [W_off|W_attn] cols
// (T-4)*64..), slot = (T*32 + g)*64 + nl, 8 f16 per slot (k = g*8+e).
__global__ __launch_bounds__(256) void prep_w(
    const float* __restrict__ W_val, const float* __restrict__ W_off,
    const float* __restrict__ W_attn, _Float16* __restrict__ wtf)
{
    const int slot = blockIdx.x * 256 + threadIdx.x;   // 0..20479
    const int T = slot >> 11;
    const int rem = slot & 2047;
    const int g = rem >> 6, nl = rem & 63;
    half8 h;
#pragma unroll
    for (int e = 0; e < 8; ++e) {
        const int k = g * 8 + e;
        float v;
        if (T < 4) {
            v = W_val[k * 256 + T * 64 + nl];
        } else {
            const int n2 = (T - 4) * 64 + nl;
            v = (n2 < 256) ? W_off[k * 256 + n2] : W_attn[k * 128 + (n2 - 256)];
        }
        h[e] = (_Float16)v;
    }
    *(half8*)(wtf + ((size_t)slot << 3)) = h;
}

// -------- fused GEMM1+GEMM2, 64x64 tiles, one-shot K=256, zero barriers -------
__global__ __launch_bounds__(256) void gemm12_cvt(
    const float* __restrict__ value, const float* __restrict__ query,
    const _Float16* __restrict__ wtf,
    const float* __restrict__ b_val, const float* __restrict__ b_off,
    const float* __restrict__ b_attn,
    _Float16* __restrict__ valh, _Float16* __restrict__ offh)
{
    // A tile: row-major [64][256] f16 (pitch 512B), XOR-swizzled within row
    __shared__ _Float16 Asw[64 * 256];   // 32KB

    // XCD chunk swizzle: 3400 = 8 * 425; consecutive logical ids (sharing an
    // A panel) land on the SAME XCD, 8 dispatch slots apart.
    const int bid = ((int)blockIdx.x % 8) * 425 + ((int)blockIdx.x / 8);

    const bool g1 = bid < 1360;
    const int id = g1 ? bid : bid - 1360;
    const int mt = g1 ? (id >> 2) : (id / 6);
    const int nt = g1 ? (id & 3) : (id % 6);
    const int NN = g1 ? 256 : 384;
    const float* A = g1 ? value : query;
    _Float16* C = g1 ? valh : offh;
    const int bm = mt * 64;
    const int bn = nt * 64;
    const int T  = g1 ? nt : 4 + nt;

    const int tid = threadIdx.x;
    const int wave = tid >> 6, lane = tid & 63;
    const int ml = lane & 15, q = lane >> 4;

    // ---- stage A (wave-private 16 rows; one full row per wave-instruction) ---
    const int rbase = wave * 16;
    float4 pa[16];
#pragma unroll
    for (int rr = 0; rr < 16; ++rr)
        pa[rr] = *(const float4*)(A + (size_t)(bm + rbase + rr) * 256 + lane * 4);
#pragma unroll
    for (int rr = 0; rr < 16; ++rr) {
        const int row = rbase + rr;
        const float4 v = pa[rr];
        const half4 h = {(_Float16)v.x, (_Float16)v.y, (_Float16)v.z, (_Float16)v.w};
        const int wbyte = row * 512 + ((lane * 8) ^ ((row & 7) << 4));
        *(half4*)(Asw + (wbyte >> 1)) = h;
    }

    // ---- MFMA loop: af from swizzled LDS (own rows), bf direct from global ---
    const _Float16* bptr = wtf + ((size_t)T << 14) + q * 512 + ml * 8;
    const int arow = rbase + ml;
    const int abase = arow * 512;
    const int swl = (ml & 7) << 4;

    const f32x4 zero4 = {0.f, 0.f, 0.f, 0.f};
    f32x4 acc[4] = {zero4, zero4, zero4, zero4};
    half8 bf0[4], bf1[4], af0, af1;

#define BFLOAD(dst, kt)                                                        \
    {                                                                          \
        _Pragma("unroll") for (int j = 0; j < 4; ++j)                          \
            dst[j] = *(const half8*)(bptr + (kt) * 2048 + j * 128);            \
    }
#define AFLOAD(kt) \
    (*(const half8*)(Asw + ((abase + (((kt) * 64 + q * 16) ^ swl)) >> 1)))
#define MSTEP(bf, af)                                                          \
    {                                                                          \
        _Pragma("unroll") for (int j = 0; j < 4; ++j)                          \
            acc[j] = __builtin_amdgcn_mfma_f32_16x16x32_f16(af, bf[j],         \
                                                            acc[j], 0, 0, 0); \
    }

    BFLOAD(bf0, 0); BFLOAD(bf1, 1);
    af0 = AFLOAD(0);
    af1 = AFLOAD(1); MSTEP(bf0, af0); BFLOAD(bf0, 2);
    af0 = AFLOAD(2); MSTEP(bf1, af1); BFLOAD(bf1, 3);
    af1 = AFLOAD(3); MSTEP(bf0, af0); BFLOAD(bf0, 4);
    af0 = AFLOAD(4); MSTEP(bf1, af1); BFLOAD(bf1, 5);
    af1 = AFLOAD(5); MSTEP(bf0, af0); BFLOAD(bf0, 6);
    af0 = AFLOAD(6); MSTEP(bf1, af1); BFLOAD(bf1, 7);
    af1 = AFLOAD(7); MSTEP(bf0, af0);
    MSTEP(bf1, af1);

#undef BFLOAD
#undef AFLOAD
#undef MSTEP

    // ---- epilogue ----
    const int r0 = q * 4;
#pragma unroll
    for (int j = 0; j < 4; ++j) {
        const int col = bn + j * 16 + ml;
        const float bj = g1 ? b_val[col] : (col < 256 ? b_off[col] : b_attn[col - 256]);
        const size_t rbaseC = (size_t)(bm + rbase + r0) * NN + col;
#pragma unroll
        for (int r = 0; r < 4; ++r)
            C[rbaseC + (size_t)r * NN] = (_Float16)(acc[j][r] + bj);
    }
}

// -------- R4 GEMM core (DMA staging, pitch 32) for the final GEMM -------------
__device__ __forceinline__ void gemm_core(
    const _Float16* __restrict__ A, const _Float16* __restrict__ Bt,
    const float* __restrict__ bias, float* __restrict__ Cv,
    int NN, int mt, int nt)
{
    __shared__ _Float16 Ah[128 * 32];
    __shared__ _Float16 Bh[64 * 32];

    const int tid = threadIdx.x;
    const int bm = mt * 128;
    const int bn = nt * 64;
    const int wave = tid >> 6, lane = tid & 63;
    const int wm = (wave & 1) * 64, wn = (wave >> 1) * 32;
    const int ml = lane & 15, kq = (lane >> 4) * 8;
    const int lr = lane >> 2;
    const int lk = (lane & 3) * 8;

    const f32x4 zero4 = {0.f, 0.f, 0.f, 0.f};
    f32x4 acc[4][2];
#pragma unroll
    for (int i = 0; i < 4; ++i)
#pragma unroll
        for (int j = 0; j < 2; ++j) acc[i][j] = zero4;

    for (int kt = 0; kt < 8; ++kt) {
        const int k0 = kt * 32;
        __syncthreads();
#pragma unroll
        for (int t = 0; t < 2; ++t) {
            const int row = wave * 32 + t * 16;
            load_lds16(A + (size_t)(bm + row + lr) * 256 + k0 + lk,
                       Ah + (size_t)row * 32);
        }
        {
            const int row = wave * 16;
            load_lds16(Bt + (size_t)(bn + row + lr) * 256 + k0 + lk,
                       Bh + (size_t)row * 32);
        }
        __syncthreads();

        half8 af[4], bf[2];
#pragma unroll
        for (int i = 0; i < 4; ++i)
            af[i] = *(const half8*)(Ah + (wm + i * 16 + ml) * 32 + kq);
#pragma unroll
        for (int j = 0; j < 2; ++j)
            bf[j] = *(const half8*)(Bh + (wn + j * 16 + ml) * 32 + kq);
#pragma unroll
        for (int i = 0; i < 4; ++i)
#pragma unroll
            for (int j = 0; j < 2; ++j)
                acc[i][j] = __builtin_amdgcn_mfma_f32_16x16x32_f16(af[i], bf[j], acc[i][j], 0, 0, 0);
    }

    const int r0 = (lane >> 4) * 4;
#pragma unroll
    for (int j = 0; j < 2; ++j) {
        const int col = bn + wn + j * 16 + ml;
        const float bj = bias[col];
#pragma unroll
        for (int i = 0; i < 4; ++i) {
            const size_t rbase = (size_t)(bm + wm + i * 16 + r0) * NN + col;
#pragma unroll
            for (int r = 0; r < 4; ++r)
                Cv[rbase + (size_t)r * NN] = acc[i][j][r] + bj;
        }
    }
}

__global__ __launch_bounds__(256) void gemm_single(
    const _Float16* __restrict__ A, const _Float16* __restrict__ Bt,
    const float* __restrict__ bias, float* __restrict__ Cv)
{
    const int id = blockIdx.x;
    gemm_core(A, Bt, bias, Cv, 256, id >> 2, id & 3);
}

// ---------------- sampler: group-dedup'd scalar phase + batched gathers -------
__global__ __launch_bounds__(256, 4) void sample_f16(
    const _Float16* __restrict__ valh,   // [M,256] f16
    const float* __restrict__ refp,      // [B,Lq,4,2]
    const _Float16* __restrict__ offh,   // [M,384] f16: 0-255 offsets, 256-383 logits
    const float* __restrict__ W_out,     // [256,256] f32 (k-major)
    _Float16* __restrict__ wto,          // [256,256] f16 (n-major, k-contig)
    _Float16* __restrict__ acc_out)      // [M,256] f16
{
    // fold W_out transpose into the first 256 blocks (consumed next dispatch)
    if (blockIdx.x < 256)
        wto[blockIdx.x * 256 + threadIdx.x] =
            (_Float16)W_out[threadIdx.x * 256 + blockIdx.x];

    const int wave = threadIdx.x >> 6, lane = threadIdx.x & 63;
    const int q2 = lane >> 5, sl = lane & 31;
    const int bq = blockIdx.x * 8 + wave * 2 + q2;    // 0..21759
    const int b = bq / 5440;
    const int h = sl >> 2;          // head
    const int t = sl & 3;           // dual role: my LEVEL (scalar phase) and d8 octet (gather)
    const int d8 = t * 8;

    // ---------- scalar phase: lane t computes level t's 4 points ----------
    const int Wt = 64 >> t;                       // {64,32,16,8}
    const float fW = (float)Wt;

    const half8 ofr = *(const half8*)(offh + (size_t)bq * 384 + h * 32 + t * 8);
    const half4 lgt = *(const half4*)(offh + (size_t)bq * 384 + 256 + h * 16 + t * 4);
    const float2 rxy = *(const float2*)(refp + (size_t)bq * 8 + t * 2);

    float lg[4];
#pragma unroll
    for (int p = 0; p < 4; ++p) lg[p] = (float)lgt[p];

    // group softmax: 4-lane butterfly (lanes t=0..3 share (bq,h))
    float mx = fmaxf(fmaxf(lg[0], lg[1]), fmaxf(lg[2], lg[3]));
    mx = fmaxf(mx, __shfl_xor(mx, 1));
    mx = fmaxf(mx, __shfl_xor(mx, 2));
    float s = 0.f;
#pragma unroll
    for (int p = 0; p < 4; ++p) { lg[p] = __expf(lg[p] - mx); s += lg[p]; }
    s += __shfl_xor(s, 1);
    s += __shfl_xor(s, 2);
    const float inv = 1.f / s;

    // per-corner pack: row(<=4095) << 16 | f16(weight)
    unsigned pk[16];
#pragma unroll
    for (int p = 0; p < 4; ++p) {
        const float aw = lg[p] * inv;
        const float ox = (float)ofr[p * 2];
        const float oy = (float)ofr[p * 2 + 1];
        const float x = fmaf(rxy.x, fW, ox) - 0.5f;
        const float y = fmaf(rxy.y, fW, oy) - 0.5f;
        const float x0f = floorf(x), y0f = floorf(y);
        const int x0 = (int)x0f, y0 = (int)y0f;
        const float wx = x - x0f, wy = y - y0f;
        const bool okx0 = ((unsigned)x0 < (unsigned)Wt);
        const bool okx1 = ((unsigned)(x0 + 1) < (unsigned)Wt);
        const bool oky0 = ((unsigned)y0 < (unsigned)Wt);
        const bool oky1 = ((unsigned)(y0 + 1) < (unsigned)Wt);
        const int xc0 = min(max(x0, 0), Wt - 1);
        const int xc1 = min(max(x0 + 1, 0), Wt - 1);
        const int yc0 = min(max(y0, 0), Wt - 1);
        const int yc1 = min(max(y0 + 1, 0), Wt - 1);
        const _Float16 w0 = (_Float16)((okx0 & oky0) ? (1.f - wx) * (1.f - wy) * aw : 0.f);
        const _Float16 w1 = (_Float16)((okx1 & oky0) ? wx * (1.f - wy) * aw : 0.f);
        const _Float16 w2 = (_Float16)((okx0 & oky1) ? (1.f - wx) * wy * aw : 0.f);
        const _Float16 w3 = (_Float16)((okx1 & oky1) ? wx * wy * aw : 0.f);
        pk[p * 4 + 0] = ((unsigned)(yc0 * Wt + xc0) << 16) |
                        (unsigned)__builtin_bit_cast(unsigned short, w0);
        pk[p * 4 + 1] = ((unsigned)(yc0 * Wt + xc1) << 16) |
                        (unsigned)__builtin_bit_cast(unsigned short, w1);
        pk[p * 4 + 2] = ((unsigned)(yc1 * Wt + xc0) << 16) |
                        (unsigned)__builtin_bit_cast(unsigned short, w2);
        pk[p * 4 + 3] = ((unsigned)(yc1 * Wt + xc1) << 16) |
                        (unsigned)__builtin_bit_cast(unsigned short, w3);
    }

    // ---------- gather phase: all lanes, per level, via group exchange ----
    const int starts_[4] = {0, 4096, 5120, 5376};
    const int gbase = lane & ~3;                  // group leader lane

    half8 acc = splat8((_Float16)0.f);
#pragma unroll
    for (int l = 0; l < 4; ++l) {
        const _Float16* vbase = valh + ((size_t)(b * 5440 + starts_[l])) * 256 + h * 32 + d8;
        const int src = gbase + l;

        unsigned q_[16];
#pragma unroll
        for (int c = 0; c < 16; ++c)
            q_[c] = (unsigned)__shfl((int)pk[c], src);

        // pin: all 16 loads issue before any consumer (progressive vmcnt drain)
        __builtin_amdgcn_sched_barrier(0);
        half8 c_[16];
#pragma unroll
        for (int c = 0; c < 16; ++c)
            c_[c] = *(const half8*)(vbase + ((size_t)(q_[c] >> 16) << 8));
        __builtin_amdgcn_sched_barrier(0);
#pragma unroll
        for (int c = 0; c < 16; ++c)
            acc += c_[c] * splat8(__builtin_bit_cast(_Float16, (unsigned short)(q_[c] & 0xffffu)));
    }

    *(half8*)(acc_out + (size_t)bq * 256 + h * 32 + d8) = acc;
}

extern "C" void kernel_launch(void* const* d_in, const int* in_sizes, int n_in,
                              void* d_out, int out_size, void* d_ws, size_t ws_size,
                              hipStream_t stream) {
    const float* query  = (const float*)d_in[0];
    const float* refp   = (const float*)d_in[1];
    const float* value  = (const float*)d_in[2];
    const float* W_off  = (const float*)d_in[3];
    const float* b_off  = (const float*)d_in[4];
    const float* W_attn = (const float*)d_in[5];
    const float* b_attn = (const float*)d_in[6];
    const float* W_val  = (const float*)d_in[7];
    const float* b_val  = (const float*)d_in[8];
    const float* W_out  = (const float*)d_in[9];
    const float* b_out  = (const float*)d_in[10];
    float* out = (float*)d_out;

    const size_t M = M_TOTAL;

    _Float16* valh  = (_Float16*)d_ws;                // M*256
    _Float16* offh  = valh + M * 256;                 // M*384
    _Float16* acc16 = offh + M * 384;                 // M*256
    _Float16* wto   = acc16 + M * 256;                // 256*256
    _Float16* wtf   = wto + 256 * 256;                // 10*32*64*8 = 163840

    dim3 blk(256);
    prep_w<<<dim3(80), blk, 0, stream>>>(W_val, W_off, W_attn, wtf);
    gemm12_cvt<<<dim3(3400), blk, 0, stream>>>(
        value, query, wtf, b_val, b_off, b_attn, valh, offh);
    sample_f16<<<dim3(M / 8), blk, 0, stream>>>(valh, refp, offh, W_out, wto, acc16);
    gemm_single<<<dim3(680), blk, 0, stream>>>(acc16, wto, b_out, out);
}